// Round 19
// baseline (16465.814 us; speedup 1.0000x reference)
//
#include <hip/hip_runtime.h>

#define BB 512
#define TT 128
#define EE 512
#define HH 256
#define VV 39
#define H3 768
#define H2 512
#define TM1 127
#define NEGF (-3.402823466e38f)

typedef unsigned short u16;
typedef unsigned char u8;
typedef unsigned int u32;
typedef __attribute__((ext_vector_type(8))) short s16x8;
typedef __attribute__((ext_vector_type(4))) float f32x4;
typedef __attribute__((ext_vector_type(2))) unsigned int u32x2;
typedef __attribute__((ext_vector_type(4))) unsigned int u32x4;

__device__ __forceinline__ float b2f(u16 u){ u32 x=((u32)u)<<16; return __uint_as_float(x); }
__device__ __forceinline__ u16 f2b(float f){ u32 x=__float_as_uint(f); u32 r=(x+0x7fffu+((x>>16)&1u))>>16; return (u16)r; }
__device__ __forceinline__ float sigm(float x){ return 1.f/(1.f+__expf(-x)); }
__device__ __forceinline__ float tanh1(float x){ float t=__expf(2.f*x); return 1.f-2.f/(t+1.f); }
__device__ __forceinline__ float bfl(u32 u){ return __uint_as_float(u<<16); }
__device__ __forceinline__ float bfh(u32 u){ return __uint_as_float(u & 0xffff0000u); }
__device__ __forceinline__ float f8f(u32 x){
  u32 m = x & 0x7Fu;
  u32 h = ((x & 0x80u) << 8) | (m ? ((m<<4) + 0x3C00u) : 0u);
  return __uint_as_float(h << 16);
}
__device__ __forceinline__ u8 f2f8(float f){
  u32 b = __float_as_uint(f);
  u32 s = (b>>31)<<7;
  u32 mag = b & 0x7fffffffu;
  if (mag < 0x3C800000u) return (u8)s;
  u32 r = mag + 0x7FFFFu + ((mag>>20)&1u);
  if (r >= 0x43E80000u) return (u8)(s | 0x7Eu);
  u32 E = (r>>23) - 120u; u32 M = (r>>20)&7u;
  return (u8)(s | (E<<3) | M);
}

#define MFMA __builtin_amdgcn_mfma_f32_16x16x32_bf16
#define MFMA8 __builtin_amdgcn_mfma_f32_16x16x32_fp8_fp8

// ---------------------------------------------------------------------------
__global__ __launch_bounds__(256) void k_tables(
    const float* __restrict__ src_emb, const float* __restrict__ trg_emb,
    const float* __restrict__ Wih_f, const float* __restrict__ bih_f,
    const float* __restrict__ Wih_b, const float* __restrict__ bih_b,
    const float* __restrict__ dec_Wih, const float* __restrict__ dec_bih,
    const float* __restrict__ pre_W,
    float* __restrict__ tab_gi_f, float* __restrict__ tab_gi_b,
    float* __restrict__ tab_dec, float* __restrict__ tab_pre)
{
  int v = blockIdx.x;
  int y = blockIdx.y;
  int tid = threadIdx.x;
  if (y < 9){
    int seg = y/3, part = y%3;
    int n = part*256 + tid;
    const float* emb; const float* W; const float* bias; float* out; int ldw;
    if (seg==0){ emb=src_emb; W=Wih_f; bias=bih_f; out=tab_gi_f; ldw=EE; }
    else if (seg==1){ emb=src_emb; W=Wih_b; bias=bih_b; out=tab_gi_b; ldw=EE; }
    else { emb=trg_emb; W=dec_Wih; bias=dec_bih; out=tab_dec; ldw=EE+H2; }
    float acc = bias[n];
    const float* er = emb + (size_t)v*EE;
    const float* wr = W + (size_t)n*ldw;
    for (int k=0;k<EE;k++) acc += er[k]*wr[k];
    out[(size_t)v*H3 + n] = acc;
  } else {
    int n = tid;
    float acc = 0.f;
    const float* er = trg_emb + (size_t)v*EE;
    const float* wr = pre_W + (size_t)n*1280;
    for (int k=0;k<EE;k++) acc += er[k]*wr[k];
    tab_pre[(size_t)v*HH + n] = acc;
  }
}

__global__ __launch_bounds__(256) void k_cvt_all(
    const float* __restrict__ eWhh_f, const float* __restrict__ eWhh_b,
    const float* __restrict__ dWhh, const float* __restrict__ dWih,
    const float* __restrict__ Wk, const float* __restrict__ Wq,
    u16* __restrict__ o1, u16* __restrict__ o2, u16* __restrict__ o3,
    u16* __restrict__ o4, u16* __restrict__ o5, u16* __restrict__ o6)
{
  int idx = blockIdx.x*256 + threadIdx.x;
  const float* src; u16* dst; int cols, ld, off, rel;
  if      (idx <  196608){ rel=idx;          src=eWhh_f; dst=o1; cols=256; ld=256;  off=0;   }
  else if (idx <  393216){ rel=idx-196608;   src=eWhh_b; dst=o2; cols=256; ld=256;  off=0;   }
  else if (idx <  589824){ rel=idx-393216;   src=dWhh;   dst=o3; cols=256; ld=256;  off=0;   }
  else if (idx <  983040){ rel=idx-589824;   src=dWih;   dst=o4; cols=512; ld=1024; off=512; }
  else if (idx < 1114112){ rel=idx-983040;   src=Wk;     dst=o5; cols=512; ld=512;  off=0;   }
  else if (idx < 1179648){ rel=idx-1114112;  src=Wq;     dst=o6; cols=256; ld=256;  off=0;   }
  else return;
  int r = rel/cols, c2 = rel - r*cols;
  dst[rel] = f2b(src[(size_t)r*ld + off + c2]);
}

__global__ __launch_bounds__(256) void k_w2(const float* __restrict__ genW,
    const float* __restrict__ preW, u16* __restrict__ w2)
{
  int idx = blockIdx.x*256 + threadIdx.x;
  if (idx >= 64*512) return;
  int v = idx>>9, k = idx&511;
  float acc = 0.f;
  if (v < VV){
    for (int n=0;n<HH;n++) acc += genW[(size_t)v*HH+n]*preW[(size_t)n*1280+768+k];
  }
  w2[idx] = f2b(acc);
}
__global__ __launch_bounds__(256) void k_w3(const float* __restrict__ genW,
    const float* __restrict__ preW, u16* __restrict__ w3)
{
  int idx = blockIdx.x*256 + threadIdx.x;
  if (idx >= 64*256) return;
  int v = idx>>8, k = idx&255;
  float acc = 0.f;
  if (v < VV){
    for (int n=0;n<HH;n++) acc += genW[(size_t)v*HH+n]*preW[(size_t)n*1280+512+k];
  }
  w3[idx] = f2b(acc);
}
__global__ __launch_bounds__(256) void k_tlg(const float* __restrict__ tab_pre,
    const float* __restrict__ genW, float* __restrict__ tlg)
{
  int v1 = blockIdx.x, tid = threadIdx.x;
  if (tid < 64){
    float acc = 0.f;
    if (tid < VV){
      for (int n=0;n<HH;n++) acc += tab_pre[(size_t)v1*HH+n]*genW[(size_t)tid*HH+n];
    }
    tlg[(size_t)v1*64 + tid] = acc;
  }
}

// ---------------------------------------------------------------------------
__global__ __launch_bounds__(512) void k_enc_all(const int* __restrict__ input,
    const u16* __restrict__ wb_f, const u16* __restrict__ wb_b,
    const float* __restrict__ bhh_f, const float* __restrict__ bhh_b,
    const float* __restrict__ tab_f, const float* __restrict__ tab_b,
    float* __restrict__ h_f, float* __restrict__ h_b, u16* __restrict__ enc_out)
{
  __shared__ float gh[4][772];
  __shared__ u16 hs[16][264];
  int bx = blockIdx.x;
  int dirb = bx>>7, mt = bx&127;
  int m0 = mt*4;
  int tid = threadIdx.x;
  const float* tab = dirb? tab_b : tab_f;
  const float* bhh = dirb? bhh_b : bhh_f;
  const u16* Wb = dirb? wb_b : wb_f;
  int c = tid & 255, rh = tid>>8;
  float b_r=bhh[c], b_z=bhh[c+256], b_n=bhh[c+512];
  float hreg[2];
  hreg[0]=0.f; hreg[1]=0.f;
  int wv = tid>>6, lane = tid&63, l15 = lane&15, kg=(lane>>4)*8;
  int n0w = wv*96;
  float* hOut = dirb? h_b : h_f;
  { u16* z = &hs[0][0]; for (int e=tid; e<16*264; e+=512) z[e]=0; }
  __syncthreads();

  for (int s=1; s<=TT; s++){
    int tcol = dirb? (TT-s) : (s-1);
    #pragma unroll
    for (int r=0;r<2;r++){
      int row = rh*2 + r;
      int b = m0 + row;
      int tok = input[b*TT + tcol];
      const float* tg = tab + (size_t)tok*H3;
      float g0=0.f, g1=0.f, g2=0.f;
      if (s>1){ g0=gh[row][c]; g1=gh[row][c+256]; g2=gh[row][c+512]; }
      float rg = sigm(tg[c]     + g0 + b_r);
      float zg = sigm(tg[c+256] + g1 + b_z);
      float ng = tanh1(tg[c+512] + rg*(g2 + b_n));
      float hv = (1.f-zg)*ng + zg*hreg[r];
      hreg[r] = hv;
      u16 hb = f2b(hv);
      hs[row][c] = hb;
      enc_out[((size_t)b*TT + tcol)*H2 + (size_t)dirb*HH + c] = hb;
    }
    if (s==TT){
      #pragma unroll
      for (int r=0;r<2;r++)
        hOut[(size_t)(m0+rh*2+r)*HH + c] = hreg[r];
      break;
    }
    __syncthreads();
    f32x4 acc[6];
    #pragma unroll
    for (int nt=0;nt<6;nt++) acc[nt]=(f32x4){0.f,0.f,0.f,0.f};
    const u16* ar0 = &hs[l15][0];
    s16x8 bcur[6], bnext[6];
    #pragma unroll
    for (int nt=0;nt<6;nt++)
      bcur[nt] = *(const s16x8*)(Wb + (size_t)(n0w+nt*16+l15)*HH + kg);
    #pragma unroll
    for (int ko=0;ko<256;ko+=32){
      if (ko<224){
        #pragma unroll
        for (int nt=0;nt<6;nt++)
          bnext[nt] = *(const s16x8*)(Wb + (size_t)(n0w+nt*16+l15)*HH + ko+32 + kg);
      }
      s16x8 a0 = *(const s16x8*)(ar0 + ko + kg);
      #pragma unroll
      for (int nt=0;nt<6;nt++)
        acc[nt] = MFMA(a0, bcur[nt], acc[nt], 0,0,0);
      #pragma unroll
      for (int nt=0;nt<6;nt++) bcur[nt]=bnext[nt];
    }
    int q4 = (lane>>4)*4;
    if (q4 == 0){
      #pragma unroll
      for (int nt=0;nt<6;nt++){
        int col = n0w + nt*16 + l15;
        #pragma unroll
        for (int j=0;j<4;j++)
          gh[j][col] = acc[nt][j];
      }
    }
    __syncthreads();
  }
}

__global__ __launch_bounds__(256) void k_proj(const u16* __restrict__ enc,
    const u16* __restrict__ W, u16* __restrict__ out, int nTot)
{
  int m0 = blockIdx.x*64;
  int tid = threadIdx.x, wv = tid>>6, lane = tid&63;
  int l15 = lane&15, kg = (lane>>4)*8;
  int n0 = blockIdx.y*256 + wv*64;
  f32x4 acc[4][4];
  #pragma unroll
  for (int rt=0;rt<4;rt++)
    #pragma unroll
    for (int nt=0;nt<4;nt++) acc[rt][nt] = (f32x4){0.f,0.f,0.f,0.f};
  for (int ko=0; ko<512; ko+=32){
    s16x8 a[4], b[4];
    #pragma unroll
    for (int rt=0;rt<4;rt++) a[rt] = *(const s16x8*)(enc + (size_t)(m0+rt*16+l15)*H2 + ko + kg);
    #pragma unroll
    for (int nt=0;nt<4;nt++) b[nt] = *(const s16x8*)(W + (size_t)(n0+nt*16+l15)*H2 + ko + kg);
    #pragma unroll
    for (int rt=0;rt<4;rt++)
      #pragma unroll
      for (int nt=0;nt<4;nt++)
        acc[rt][nt] = MFMA(a[rt], b[nt], acc[rt][nt], 0,0,0);
  }
  #pragma unroll
  for (int rt=0;rt<4;rt++){
    int rbase = m0 + rt*16 + (lane>>4)*4;
    #pragma unroll
    for (int nt=0;nt<4;nt++){
      int col = n0 + nt*16 + l15;
      #pragma unroll
      for (int j=0;j<4;j++)
        out[(size_t)(rbase+j)*nTot + col] = f2b(acc[rt][nt][j]);
    }
  }
}

__global__ __launch_bounds__(256) void k_proj_f8(const u16* __restrict__ enc,
    const u16* __restrict__ W, u8* __restrict__ out, int nTot)
{
  int m0 = blockIdx.x*64;
  int tid = threadIdx.x, wv = tid>>6, lane = tid&63;
  int l15 = lane&15, kg = (lane>>4)*8;
  int n0 = blockIdx.y*256 + wv*64;
  f32x4 acc[4][4];
  #pragma unroll
  for (int rt=0;rt<4;rt++)
    #pragma unroll
    for (int nt=0;nt<4;nt++) acc[rt][nt] = (f32x4){0.f,0.f,0.f,0.f};
  for (int ko=0; ko<512; ko+=32){
    s16x8 a[4], b[4];
    #pragma unroll
    for (int rt=0;rt<4;rt++) a[rt] = *(const s16x8*)(enc + (size_t)(m0+rt*16+l15)*H2 + ko + kg);
    #pragma unroll
    for (int nt=0;nt<4;nt++) b[nt] = *(const s16x8*)(W + (size_t)(n0+nt*16+l15)*H2 + ko + kg);
    #pragma unroll
    for (int rt=0;rt<4;rt++)
      #pragma unroll
      for (int nt=0;nt<4;nt++)
        acc[rt][nt] = MFMA(a[rt], b[nt], acc[rt][nt], 0,0,0);
  }
  #pragma unroll
  for (int rt=0;rt<4;rt++){
    int rbase = m0 + rt*16 + (lane>>4)*4;
    #pragma unroll
    for (int nt=0;nt<4;nt++){
      int col = n0 + nt*16 + l15;
      #pragma unroll
      for (int j=0;j<4;j++)
        out[(size_t)(rbase+j)*nTot + col] = f2f8(acc[rt][nt][j]);
    }
  }
}

__global__ __launch_bounds__(256) void k_proj64(const u16* __restrict__ enc,
    const u16* __restrict__ W2, u16* __restrict__ out)
{
  int m0 = blockIdx.x*64;
  int tid = threadIdx.x, wv = tid>>6, lane = tid&63;
  int l15 = lane&15, kg = (lane>>4)*8;
  int n0 = wv*16;
  f32x4 acc[4];
  #pragma unroll
  for (int rt=0;rt<4;rt++) acc[rt] = (f32x4){0.f,0.f,0.f,0.f};
  for (int ko=0; ko<512; ko+=32){
    s16x8 b = *(const s16x8*)(W2 + (size_t)(n0+l15)*H2 + ko + kg);
    #pragma unroll
    for (int rt=0;rt<4;rt++){
      s16x8 a = *(const s16x8*)(enc + (size_t)(m0+rt*16+l15)*H2 + ko + kg);
      acc[rt] = MFMA(a, b, acc[rt], 0,0,0);
    }
  }
  #pragma unroll
  for (int rt=0;rt<4;rt++){
    int rbase = m0 + rt*16 + (lane>>4)*4;
    int col = n0 + l15;
    #pragma unroll
    for (int j=0;j<4;j++)
      out[(size_t)(rbase+j)*64 + col] = f2b(acc[rt][j]);
  }
}

__global__ __launch_bounds__(256) void k_bridge(const float* __restrict__ h_f,
    const float* __restrict__ h_b, const float* __restrict__ bw,
    const float* __restrict__ bb, float* __restrict__ hst)
{
  __shared__ float As[32][68];
  __shared__ float Ws[32][68];
  int n0=blockIdx.x*64, m0=blockIdx.y*64, tid=threadIdx.x;
  int ar=tid>>2, ak=(tid&3)*8;
  int rt=tid>>4, ct=tid&15;
  float acc[4][4];
  #pragma unroll
  for (int j=0;j<4;j++){
    #pragma unroll
    for (int l=0;l<4;l++) acc[j][l]=0.f;
  }
  for (int ko=0;ko<512;ko+=32){
    int k0=ko+ak;
    const float* asrc = (k0<256)? (h_f + (size_t)(m0+ar)*HH + k0)
                                : (h_b + (size_t)(m0+ar)*HH + (k0-256));
    float4 a0=*(const float4*)asrc, a1=*(const float4*)(asrc+4);
    const float* wsrc = bw + (size_t)(n0+ar)*H2 + k0;
    float4 w0=*(const float4*)wsrc, w1=*(const float4*)(wsrc+4);
    __syncthreads();
    As[ak+0][ar]=a0.x; As[ak+1][ar]=a0.y; As[ak+2][ar]=a0.z; As[ak+3][ar]=a0.w;
    As[ak+4][ar]=a1.x; As[ak+5][ar]=a1.y; As[ak+6][ar]=a1.z; As[ak+7][ar]=a1.w;
    Ws[ak+0][ar]=w0.x; Ws[ak+1][ar]=w0.y; Ws[ak+2][ar]=w0.z; Ws[ak+3][ar]=w0.w;
    Ws[ak+4][ar]=w1.x; Ws[ak+5][ar]=w1.y; Ws[ak+6][ar]=w1.z; Ws[ak+7][ar]=w1.w;
    __syncthreads();
    #pragma unroll
    for (int kk=0;kk<32;kk++){
      float4 a=*(const float4*)&As[kk][rt*4];
      float4 w=*(const float4*)&Ws[kk][ct*4];
      float a4[4]={a.x,a.y,a.z,a.w};
      float w4[4]={w.x,w.y,w.z,w.w};
      #pragma unroll
      for (int j=0;j<4;j++){
        #pragma unroll
        for (int l=0;l<4;l++) acc[j][l]+=a4[j]*w4[l];
      }
    }
  }
  #pragma unroll
  for (int j=0;j<4;j++){
    int row=m0+rt*4+j;
    #pragma unroll
    for (int l=0;l<4;l++){
      int col=n0+ct*4+l;
      hst[(size_t)row*HH+col]=tanh1(acc[j][l]+bb[col]);
    }
  }
}

// ---------------------------------------------------------------------------
// Row-local persistent decoder, 1 row/block. grid(512) x 256 (1 block/CU,
// 2 scheduling rounds). eih8 TRANSPOSED into LDS once (pad-136 rows); gic via
// fp8 MFMA; zero inter-block communication; weights L2-resident.
__global__ __launch_bounds__(256,1) void k_dec_row1(
    const int* __restrict__ input,
    const float* __restrict__ tab_dec, const float* __restrict__ tab_lgt,
    const float* __restrict__ bhh, const float* __restrict__ We,
    const u16* __restrict__ whh, const u16* __restrict__ wq,
    const u16* __restrict__ w3,
    const u16* __restrict__ pk, const u8* __restrict__ eih8,
    const u16* __restrict__ e2, const float* __restrict__ hst,
    float* __restrict__ nll)
{
  __shared__ __align__(16) u8 eT[768*136];     // 104448: eT[n][t] fp8
  __shared__ __align__(16) u16 e2L[128][64];   // 16384
  __shared__ u16 hsb[16][264];                 // 8448 (row 0 real)
  __shared__ float ghL[H3];                    // 3072
  __shared__ float gicS[H3];                   // 3072
  __shared__ float lgcS[64];                   // 256
  __shared__ float qS[HH];                     // 1024
  __shared__ float hL[HH];                     // 1024
  __shared__ float aL[TT];                     // 512
  __shared__ __align__(8) u8 a8L[TT];          // 128
  __shared__ float lgtS[64];                   // 256
  __shared__ int stok[TT];                     // 512

  int b = blockIdx.x, tid = threadIdx.x;
  int wv = tid>>6, lane = tid&63, l15 = lane&15, kg = (lane>>4)*8;

  // ---- init
  { u16* z = &hsb[0][0]; for (int e=tid; e<16*264; e+=256) z[e]=0; }
  if (tid < TT) stok[tid] = input[b*TT + tid];
  hL[tid] = hst[(size_t)b*HH + tid];
  float b_r = bhh[tid], b_z = bhh[tid+256], b_n = bhh[tid+512];
  float4 weL = *(const float4*)(We + lane*4);
  // pk row resident in VGPRs: wave wv owns t in [wv*32,+32), lane dims 4l..+3
  u32x2 kv[32];
  {
    const u16* pkb = pk + ((size_t)b*TT + wv*32)*HH + lane*4;
    #pragma unroll
    for (int tt=0; tt<32; tt++)
      kv[tt] = *(const u32x2*)(pkb + (size_t)tt*HH);
  }
  // stage eT (transpose [t][n] -> [n][t], pad 136) and e2L (one-time)
  {
    const u8* src = eih8 + (size_t)b*TT*H3;
    for (int idx=tid; idx<6144; idx+=256){
      int t = idx/48, ng = (idx%48)*16;
      u32x4 v = *(const u32x4*)(src + (size_t)t*H3 + ng);
      const u8* pb = (const u8*)&v;
      #pragma unroll
      for (int i=0;i<16;i++) eT[(size_t)(ng+i)*136 + t] = pb[i];
    }
    const u16* s2 = e2 + (size_t)b*TT*64;
    for (int idx=tid; idx<1024; idx+=256)
      *(u32x4*)(&e2L[0][0] + idx*8) = *(const u32x4*)(s2 + idx*8);
  }
  __syncthreads();
  hsb[0][tid] = f2b(hL[tid]);
  float nlacc = 0.f;
  __syncthreads();

  // GHQ: gh = h@Whh^T (N=768), q = h@Wq^T (N=256); M=16-pad MFMA, row 0 real
  #define GHQ_P {                                                              \
    f32x4 acc6[12];                                                            \
    _Pragma("unroll")                                                          \
    for (int nt=0;nt<12;nt++) acc6[nt]=(f32x4){0.f,0.f,0.f,0.f};               \
    _Pragma("unroll")                                                          \
    for (int ko=0;ko<256;ko+=32){                                              \
      s16x8 b6[12];                                                            \
      _Pragma("unroll")                                                        \
      for (int nt=0;nt<12;nt++)                                                \
        b6[nt] = *(const s16x8*)(whh + (size_t)(wv*192+nt*16+l15)*HH + ko + kg); \
      s16x8 a0 = *(const s16x8*)&hsb[l15][ko+kg];                              \
      _Pragma("unroll")                                                        \
      for (int nt=0;nt<12;nt++) acc6[nt]=MFMA(a0,b6[nt],acc6[nt],0,0,0);       \
    }                                                                          \
    if (lane<16){                                                              \
      _Pragma("unroll")                                                        \
      for (int nt=0;nt<12;nt++) ghL[wv*192+nt*16+l15]=acc6[nt][0];             \
    }                                                                          \
    f32x4 accq[4];                                                             \
    _Pragma("unroll")                                                          \
    for (int nt=0;nt<4;nt++) accq[nt]=(f32x4){0.f,0.f,0.f,0.f};                \
    _Pragma("unroll")                                                          \
    for (int ko=0;ko<256;ko+=32){                                              \
      s16x8 a0 = *(const s16x8*)&hsb[l15][ko+kg];                              \
      _Pragma("unroll")                                                        \
      for (int nt=0;nt<4;nt++){                                                \
        s16x8 bq = *(const s16x8*)(wq + (size_t)(wv*64+nt*16+l15)*HH + ko + kg); \
        accq[nt]=MFMA(a0,bq,accq[nt],0,0,0);                                   \
      }                                                                        \
    }                                                                          \
    if (lane<16){                                                              \
      _Pragma("unroll")                                                        \
      for (int nt=0;nt<4;nt++) qS[wv*64+nt*16+l15]=accq[nt][0];                \
    }                                                                          \
  }
  GHQ_P
  __syncthreads();

  for (int j=0; j<TM1; j++){
    // ---- e[t] = We . tanh(q + pk[t])
    {
      float4 qq = *(const float4*)&qS[lane*4];
      #pragma unroll 4
      for (int tt=0; tt<32; tt++){
        u32x2 pp = kv[tt];
        float sE = tanh1(qq.x+bfl(pp.x))*weL.x + tanh1(qq.y+bfh(pp.x))*weL.y
                 + tanh1(qq.z+bfl(pp.y))*weL.z + tanh1(qq.w+bfh(pp.y))*weL.w;
        #pragma unroll
        for (int off=32; off; off>>=1) sE += __shfl_xor(sE, off);
        if (lane==0) aL[wv*32+tt] = stok[wv*32+tt] ? sE : NEGF;
      }
    }
    __syncthreads();
    if (wv==0){   // softmax + fp8 quantize of a
      float v0 = aL[lane], v1 = aL[64+lane];
      float m = fmaxf(v0,v1);
      #pragma unroll
      for (int off=32; off; off>>=1) m = fmaxf(m, __shfl_xor(m,off));
      float p0 = __expf(v0-m), p1 = __expf(v1-m);
      float sS = p0+p1;
      #pragma unroll
      for (int off=32; off; off>>=1) sS += __shfl_xor(sS,off);
      float inv = 1.f/sS;
      float a0 = p0*inv, a1 = p1*inv;
      aL[lane] = a0; aL[64+lane] = a1;
      a8L[lane] = f2f8(a0); a8L[64+lane] = f2f8(a1);
    }
    __syncthreads();
    // ---- gic = a @ eT via fp8 MFMA (waves 0,2,3); lgc = a @ e2 (wave 1)
    if (wv != 1){
      int wq3 = (wv==0)? 0 : (wv-1);
      f32x4 acc[16];
      #pragma unroll
      for (int nt=0;nt<16;nt++) acc[nt]=(f32x4){0.f,0.f,0.f,0.f};
      #pragma unroll
      for (int ks=0;ks<4;ks++){
        long av;
        {
          u32x2 t8 = *(const u32x2*)&a8L[ks*32 + kg];
          if (l15){ t8.x = 0u; t8.y = 0u; }
          __builtin_memcpy(&av, &t8, 8);
        }
        #pragma unroll
        for (int nt=0;nt<16;nt++){
          int n = wq3*256 + nt*16 + l15;
          u32x2 b8 = *(const u32x2*)&eT[(size_t)n*136 + ks*32 + kg];
          long bv; __builtin_memcpy(&bv, &b8, 8);
          acc[nt] = MFMA8(av, bv, acc[nt], 0,0,0);
        }
      }
      if (lane < 16){
        #pragma unroll
        for (int nt=0;nt<16;nt++)
          gicS[wq3*256 + nt*16 + l15] = acc[nt][0];
      }
    } else {
      float lg = 0.f;
      #pragma unroll 4
      for (int t=0;t<TT;t++) lg += aL[t]*b2f(e2L[t][lane]);
      lgcS[lane] = lg;
    }
    __syncthreads();
    // ---- gates -> h_{j+1}
    {
      int tok = stok[j];
      const float* tg = tab_dec + (size_t)tok*H3;
      float rg = sigm(tg[tid]     + gicS[tid]     + ghL[tid]     + b_r);
      float zg = sigm(tg[tid+256] + gicS[tid+256] + ghL[tid+256] + b_z);
      float ng = tanh1(tg[tid+512] + gicS[tid+512] + rg*(ghL[tid+512] + b_n));
      float hv = (1.f-zg)*ng + zg*hL[tid];
      hL[tid] = hv;
      hsb[0][tid] = f2b(hv);
    }
    __syncthreads();
    // ---- logits (wave 0) then gh/q for next step (all waves)
    if (wv==0){
      f32x4 accL[4];
      #pragma unroll
      for (int nt=0;nt<4;nt++) accL[nt]=(f32x4){0.f,0.f,0.f,0.f};
      #pragma unroll
      for (int ko=0;ko<256;ko+=32){
        s16x8 a0 = *(const s16x8*)&hsb[l15][ko+kg];
        #pragma unroll
        for (int nt=0;nt<4;nt++){
          s16x8 bf = *(const s16x8*)(w3 + (size_t)(nt*16+l15)*HH + ko + kg);
          accL[nt]=MFMA(a0,bf,accL[nt],0,0,0);
        }
      }
      int tok = stok[j];
      if (lane<16){
        #pragma unroll
        for (int nt=0;nt<4;nt++){
          int col = nt*16+l15;
          lgtS[col] = accL[nt][0] + tab_lgt[(size_t)tok*64 + col] + lgcS[col];
        }
      }
    }
    GHQ_P
    __syncthreads();
    // ---- nll (wave 0)
    if (wv==0){
      float v0 = lgtS[l15];
      float v1 = lgtS[l15+16];
      float v2 = (l15<7)? lgtS[l15+32] : NEGF;
      float m = fmaxf(fmaxf(v0,v1),v2);
      #pragma unroll
      for (int off=8; off; off>>=1) m = fmaxf(m, __shfl_xor(m,off));
      float pe = __expf(v0-m) + __expf(v1-m) + ((l15<7)? __expf(v2-m) : 0.f);
      #pragma unroll
      for (int off=8; off; off>>=1) pe += __shfl_xor(pe,off);
      if (lane==0){
        int ty = stok[j+1];
        if (ty != 0) nlacc += m + __logf(pe) - lgtS[ty];
      }
    }
    __syncthreads();
  }
  if (tid==0) nll[b] = nlacc;
}

__global__ __launch_bounds__(256) void k_loss(const float* __restrict__ nll,
                                              float* __restrict__ out)
{
  __shared__ float sm[256];
  int tid=threadIdx.x;
  float s = nll[tid] + nll[tid+256];
  sm[tid]=s; __syncthreads();
  for (int off=128; off; off>>=1){
    if (tid<off) sm[tid]+=sm[tid+off];
    __syncthreads();
  }
  if (tid==0) out[0]=sm[0];
}

extern "C" void kernel_launch(void* const* d_in, const int* in_sizes, int n_in,
                              void* d_out, int out_size, void* d_ws, size_t ws_size,
                              hipStream_t stream)
{
  const int*   input    = (const int*)  d_in[0];
  const float* src_emb  = (const float*)d_in[1];
  const float* trg_emb  = (const float*)d_in[2];
  const float* eWih_f   = (const float*)d_in[3];
  const float* eWhh_f   = (const float*)d_in[4];
  const float* ebih_f   = (const float*)d_in[5];
  const float* ebhh_f   = (const float*)d_in[6];
  const float* eWih_b   = (const float*)d_in[7];
  const float* eWhh_b   = (const float*)d_in[8];
  const float* ebih_b   = (const float*)d_in[9];
  const float* ebhh_b   = (const float*)d_in[10];
  const float* bridge_W = (const float*)d_in[11];
  const float* bridge_b = (const float*)d_in[12];
  const float* attn_Wk  = (const float*)d_in[13];
  const float* attn_Wq  = (const float*)d_in[14];
  const float* attn_We  = (const float*)d_in[15];
  const float* dec_Wih  = (const float*)d_in[16];
  const float* dec_Whh  = (const float*)d_in[17];
  const float* dec_bih  = (const float*)d_in[18];
  const float* dec_bhh  = (const float*)d_in[19];
  const float* pre_W    = (const float*)d_in[20];
  const float* gen_W    = (const float*)d_in[21];

  float* F = (float*)d_ws;
  size_t o=0;
  float* tab_gi_f = F+o; o+=(size_t)VV*H3;
  float* tab_gi_b = F+o; o+=(size_t)VV*H3;
  float* tab_dec  = F+o; o+=(size_t)VV*H3;
  float* tab_pre  = F+o; o+=(size_t)VV*HH;
  float* tab_lgt  = F+o; o+=(size_t)VV*64;
  float* h_f      = F+o; o+=(size_t)BB*HH;
  float* h_b      = F+o; o+=(size_t)BB*HH;
  float* hst      = F+o; o+=(size_t)BB*HH;
  float* nll      = F+o; o+=(size_t)BB;
  u16* U = (u16*)(F+o);
  size_t uo=0;
  u16* enc_out = U+uo; uo+=(size_t)BB*TT*H2;
  u16* pk      = U+uo; uo+=(size_t)BB*TT*HH;
  u16* e2      = U+uo; uo+=(size_t)BB*TT*64;
  u16* wb_ehh_f= U+uo; uo+=(size_t)H3*HH;
  u16* wb_ehh_b= U+uo; uo+=(size_t)H3*HH;
  u16* wb_dhh  = U+uo; uo+=(size_t)H3*HH;
  u16* wb_dih  = U+uo; uo+=(size_t)H3*H2;
  u16* wb_wk   = U+uo; uo+=(size_t)HH*H2;
  u16* wb_wq   = U+uo; uo+=(size_t)HH*HH;
  u16* wb_w2   = U+uo; uo+=(size_t)64*H2;
  u16* wb_w3   = U+uo; uo+=(size_t)64*HH;
  u8* eih8 = (u8*)(U+uo);   // [BB][TT][768] fp8

  dim3 blk(256,1,1);
  k_tables<<<dim3(VV,10),blk,0,stream>>>(src_emb,trg_emb,eWih_f,ebih_f,eWih_b,ebih_b,
                                         dec_Wih,dec_bih,pre_W,
                                         tab_gi_f,tab_gi_b,tab_dec,tab_pre);
  k_tlg<<<dim3(VV),blk,0,stream>>>(tab_pre,gen_W,tab_lgt);
  k_cvt_all<<<dim3(4608),blk,0,stream>>>(eWhh_f,eWhh_b,dec_Whh,dec_Wih,attn_Wk,attn_Wq,
                                         wb_ehh_f,wb_ehh_b,wb_dhh,wb_dih,wb_wk,wb_wq);
  k_w2<<<dim3(128),blk,0,stream>>>(gen_W,pre_W,wb_w2);
  k_w3<<<dim3(64),blk,0,stream>>>(gen_W,pre_W,wb_w3);
  k_enc_all<<<dim3(256),dim3(512),0,stream>>>(input,wb_ehh_f,wb_ehh_b,ebhh_f,ebhh_b,
                                              tab_gi_f,tab_gi_b,h_f,h_b,enc_out);
  k_proj<<<dim3(1024,1),blk,0,stream>>>(enc_out,wb_wk,pk,HH);
  k_proj_f8<<<dim3(1024,3),blk,0,stream>>>(enc_out,wb_dih,eih8,H3);
  k_proj64<<<dim3(1024),blk,0,stream>>>(enc_out,wb_w2,e2);
  k_bridge<<<dim3(4,8),blk,0,stream>>>(h_f,h_b,bridge_W,bridge_b,hst);
  k_dec_row1<<<dim3(512),blk,0,stream>>>(input,tab_dec,tab_lgt,dec_bhh,attn_We,
                                         wb_dhh,wb_wq,wb_w3,
                                         pk,eih8,e2,hst,nll);
  k_loss<<<dim3(1),blk,0,stream>>>(nll,(float*)d_out);
}

// Round 20
// 7164.069 us; speedup vs baseline: 2.2984x; 2.2984x over previous
//
#include <hip/hip_runtime.h>

#define BB 512
#define TT 128
#define EE 512
#define HH 256
#define VV 39
#define H3 768
#define H2 512
#define TM1 127
#define NEGF (-3.402823466e38f)

typedef unsigned short u16;
typedef unsigned char u8;
typedef unsigned int u32;
typedef __attribute__((ext_vector_type(8))) short s16x8;
typedef __attribute__((ext_vector_type(4))) float f32x4;
typedef __attribute__((ext_vector_type(2))) unsigned int u32x2;
typedef __attribute__((ext_vector_type(4))) unsigned int u32x4;

__device__ __forceinline__ float b2f(u16 u){ u32 x=((u32)u)<<16; return __uint_as_float(x); }
__device__ __forceinline__ u16 f2b(float f){ u32 x=__float_as_uint(f); u32 r=(x+0x7fffu+((x>>16)&1u))>>16; return (u16)r; }
__device__ __forceinline__ float sigm(float x){ return 1.f/(1.f+__expf(-x)); }
__device__ __forceinline__ float tanh1(float x){ float t=__expf(2.f*x); return 1.f-2.f/(t+1.f); }
__device__ __forceinline__ float bfl(u32 u){ return __uint_as_float(u<<16); }
__device__ __forceinline__ float bfh(u32 u){ return __uint_as_float(u & 0xffff0000u); }
__device__ __forceinline__ float f8f(u32 x){
  u32 m = x & 0x7Fu;
  u32 h = ((x & 0x80u) << 8) | (m ? ((m<<4) + 0x3C00u) : 0u);
  return __uint_as_float(h << 16);
}
__device__ __forceinline__ u8 f2f8(float f){
  u32 b = __float_as_uint(f);
  u32 s = (b>>31)<<7;
  u32 mag = b & 0x7fffffffu;
  if (mag < 0x3C800000u) return (u8)s;
  u32 r = mag + 0x7FFFFu + ((mag>>20)&1u);
  if (r >= 0x43E80000u) return (u8)(s | 0x7Eu);
  u32 E = (r>>23) - 120u; u32 M = (r>>20)&7u;
  return (u8)(s | (E<<3) | M);
}

#define MFMA __builtin_amdgcn_mfma_f32_16x16x32_bf16

__device__ __forceinline__ u32 aload(const u32* p){
  return __hip_atomic_load(p, __ATOMIC_RELAXED, __HIP_MEMORY_SCOPE_AGENT);
}
__device__ __forceinline__ void astore(u32* p, u32 v){
  __hip_atomic_store(p, v, __ATOMIC_RELAXED, __HIP_MEMORY_SCOPE_AGENT);
}
#define QF(g) ((g)*16)

// ---------------------------------------------------------------------------
__global__ __launch_bounds__(256) void k_tables(
    const float* __restrict__ src_emb, const float* __restrict__ trg_emb,
    const float* __restrict__ Wih_f, const float* __restrict__ bih_f,
    const float* __restrict__ Wih_b, const float* __restrict__ bih_b,
    const float* __restrict__ dec_Wih, const float* __restrict__ dec_bih,
    const float* __restrict__ pre_W,
    float* __restrict__ tab_gi_f, float* __restrict__ tab_gi_b,
    float* __restrict__ tab_dec, float* __restrict__ tab_pre)
{
  int v = blockIdx.x;
  int y = blockIdx.y;
  int tid = threadIdx.x;
  if (y < 9){
    int seg = y/3, part = y%3;
    int n = part*256 + tid;
    const float* emb; const float* W; const float* bias; float* out; int ldw;
    if (seg==0){ emb=src_emb; W=Wih_f; bias=bih_f; out=tab_gi_f; ldw=EE; }
    else if (seg==1){ emb=src_emb; W=Wih_b; bias=bih_b; out=tab_gi_b; ldw=EE; }
    else { emb=trg_emb; W=dec_Wih; bias=dec_bih; out=tab_dec; ldw=EE+H2; }
    float acc = bias[n];
    const float* er = emb + (size_t)v*EE;
    const float* wr = W + (size_t)n*ldw;
    for (int k=0;k<EE;k++) acc += er[k]*wr[k];
    out[(size_t)v*H3 + n] = acc;
  } else {
    int n = tid;
    float acc = 0.f;
    const float* er = trg_emb + (size_t)v*EE;
    const float* wr = pre_W + (size_t)n*1280;
    for (int k=0;k<EE;k++) acc += er[k]*wr[k];
    tab_pre[(size_t)v*HH + n] = acc;
  }
}

// bf16 weight conversions. grid(4608).
__global__ __launch_bounds__(256) void k_cvt_all(
    const float* __restrict__ eWhh_f, const float* __restrict__ eWhh_b,
    const float* __restrict__ dWhh, const float* __restrict__ dWih,
    const float* __restrict__ Wk, const float* __restrict__ Wq,
    u16* __restrict__ o1, u16* __restrict__ o2, u16* __restrict__ o3,
    u16* __restrict__ o4, u16* __restrict__ o5, u16* __restrict__ o6)
{
  int idx = blockIdx.x*256 + threadIdx.x;
  const float* src; u16* dst; int cols, ld, off, rel;
  if      (idx <  196608){ rel=idx;          src=eWhh_f; dst=o1; cols=256; ld=256;  off=0;   }
  else if (idx <  393216){ rel=idx-196608;   src=eWhh_b; dst=o2; cols=256; ld=256;  off=0;   }
  else if (idx <  589824){ rel=idx-393216;   src=dWhh;   dst=o3; cols=256; ld=256;  off=0;   }
  else if (idx <  983040){ rel=idx-589824;   src=dWih;   dst=o4; cols=512; ld=1024; off=512; }
  else if (idx < 1114112){ rel=idx-983040;   src=Wk;     dst=o5; cols=512; ld=512;  off=0;   }
  else if (idx < 1179648){ rel=idx-1114112;  src=Wq;     dst=o6; cols=256; ld=256;  off=0;   }
  else return;
  int r = rel/cols, c2 = rel - r*cols;
  dst[rel] = f2b(src[(size_t)r*ld + off + c2]);
}

// W2[v][k] = sum_n gen[v][n]*preW[n][768+k]  (64x512, bf16, v>=39 zero)
__global__ __launch_bounds__(256) void k_w2(const float* __restrict__ genW,
    const float* __restrict__ preW, u16* __restrict__ w2)
{
  int idx = blockIdx.x*256 + threadIdx.x;
  if (idx >= 64*512) return;
  int v = idx>>9, k = idx&511;
  float acc = 0.f;
  if (v < VV){
    for (int n=0;n<HH;n++) acc += genW[(size_t)v*HH+n]*preW[(size_t)n*1280+768+k];
  }
  w2[idx] = f2b(acc);
}
// W3[v][k] = sum_n gen[v][n]*preW[n][512+k]  (64x256, bf16)
__global__ __launch_bounds__(256) void k_w3(const float* __restrict__ genW,
    const float* __restrict__ preW, u16* __restrict__ w3)
{
  int idx = blockIdx.x*256 + threadIdx.x;
  if (idx >= 64*256) return;
  int v = idx>>8, k = idx&255;
  float acc = 0.f;
  if (v < VV){
    for (int n=0;n<HH;n++) acc += genW[(size_t)v*HH+n]*preW[(size_t)n*1280+512+k];
  }
  w3[idx] = f2b(acc);
}
// tab_lgt[v1][v2] = sum_n tab_pre[v1][n]*gen[v2][n]  (39x64 f32)
__global__ __launch_bounds__(256) void k_tlg(const float* __restrict__ tab_pre,
    const float* __restrict__ genW, float* __restrict__ tlg)
{
  int v1 = blockIdx.x, tid = threadIdx.x;
  if (tid < 64){
    float acc = 0.f;
    if (tid < VV){
      for (int n=0;n<HH;n++) acc += tab_pre[(size_t)v1*HH+n]*genW[(size_t)tid*HH+n];
    }
    tlg[(size_t)v1*64 + tid] = acc;
  }
}

// ---------------------------------------------------------------------------
// WHOLE encoder. grid(512): bx = dir*256 + mt (2-row tile) -> 2 blocks/CU.
__global__ __launch_bounds__(512) void k_enc_all(const int* __restrict__ input,
    const u16* __restrict__ wb_f, const u16* __restrict__ wb_b,
    const float* __restrict__ bhh_f, const float* __restrict__ bhh_b,
    const float* __restrict__ tab_f, const float* __restrict__ tab_b,
    float* __restrict__ h_f, float* __restrict__ h_b, u16* __restrict__ enc_out)
{
  __shared__ float gh[2][772];
  __shared__ u16 hs[16][264];    // rows 0,1 real; 2..15 zero (MFMA M-pad)
  int bx = blockIdx.x;
  int dirb = bx>>8, mt = bx&255;
  int m0 = mt*2;
  int tid = threadIdx.x;
  const float* tab = dirb? tab_b : tab_f;
  const float* bhh = dirb? bhh_b : bhh_f;
  const u16* Wb = dirb? wb_b : wb_f;
  int c = tid & 255, rh = tid>>8;
  float b_r=bhh[c], b_z=bhh[c+256], b_n=bhh[c+512];
  float hreg = 0.f;
  int wv = tid>>6, lane = tid&63, l15 = lane&15, kg=(lane>>4)*8;
  int n0w = wv*96;
  float* hOut = dirb? h_b : h_f;
  { u16* z = &hs[0][0]; for (int e=tid; e<16*264; e+=512) z[e]=0; }
  __syncthreads();

  for (int s=1; s<=TT; s++){
    int tcol = dirb? (TT-s) : (s-1);
    {
      int row = rh;
      int b = m0 + row;
      int tok = input[b*TT + tcol];
      const float* tg = tab + (size_t)tok*H3;
      float g0=0.f, g1=0.f, g2=0.f;
      if (s>1){ g0=gh[row][c]; g1=gh[row][c+256]; g2=gh[row][c+512]; }
      float rg = sigm(tg[c]     + g0 + b_r);
      float zg = sigm(tg[c+256] + g1 + b_z);
      float ng = tanh1(tg[c+512] + rg*(g2 + b_n));
      float hv = (1.f-zg)*ng + zg*hreg;
      hreg = hv;
      u16 hb = f2b(hv);
      hs[row][c] = hb;
      enc_out[((size_t)b*TT + tcol)*H2 + (size_t)dirb*HH + c] = hb;
    }
    if (s==TT){
      hOut[(size_t)(m0+rh)*HH + c] = hreg;
      break;
    }
    __syncthreads();
    f32x4 acc[6];
    #pragma unroll
    for (int nt=0;nt<6;nt++) acc[nt]=(f32x4){0.f,0.f,0.f,0.f};
    const u16* ar0 = &hs[l15][0];
    s16x8 bcur[6], bnext[6];
    #pragma unroll
    for (int nt=0;nt<6;nt++)
      bcur[nt] = *(const s16x8*)(Wb + (size_t)(n0w+nt*16+l15)*HH + kg);
    #pragma unroll
    for (int ko=0;ko<256;ko+=32){
      if (ko<224){
        #pragma unroll
        for (int nt=0;nt<6;nt++)
          bnext[nt] = *(const s16x8*)(Wb + (size_t)(n0w+nt*16+l15)*HH + ko+32 + kg);
      }
      s16x8 a0 = *(const s16x8*)(ar0 + ko + kg);
      #pragma unroll
      for (int nt=0;nt<6;nt++)
        acc[nt] = MFMA(a0, bcur[nt], acc[nt], 0,0,0);
      #pragma unroll
      for (int nt=0;nt<6;nt++) bcur[nt]=bnext[nt];
    }
    int q4 = (lane>>4)*4;
    if (q4 == 0){
      #pragma unroll
      for (int nt=0;nt<6;nt++){
        int col = n0w + nt*16 + l15;
        gh[0][col] = acc[nt][0];
        gh[1][col] = acc[nt][1];
      }
    }
    __syncthreads();
  }
}

// out[m][n] = enc[m].W[n] (K=512), bf16 out. grid (1024, nTot/256).
__global__ __launch_bounds__(256) void k_proj(const u16* __restrict__ enc,
    const u16* __restrict__ W, u16* __restrict__ out, int nTot)
{
  int m0 = blockIdx.x*64;
  int tid = threadIdx.x, wv = tid>>6, lane = tid&63;
  int l15 = lane&15, kg = (lane>>4)*8;
  int n0 = blockIdx.y*256 + wv*64;
  f32x4 acc[4][4];
  #pragma unroll
  for (int rt=0;rt<4;rt++)
    #pragma unroll
    for (int nt=0;nt<4;nt++) acc[rt][nt] = (f32x4){0.f,0.f,0.f,0.f};
  for (int ko=0; ko<512; ko+=32){
    s16x8 a[4], b[4];
    #pragma unroll
    for (int rt=0;rt<4;rt++) a[rt] = *(const s16x8*)(enc + (size_t)(m0+rt*16+l15)*H2 + ko + kg);
    #pragma unroll
    for (int nt=0;nt<4;nt++) b[nt] = *(const s16x8*)(W + (size_t)(n0+nt*16+l15)*H2 + ko + kg);
    #pragma unroll
    for (int rt=0;rt<4;rt++)
      #pragma unroll
      for (int nt=0;nt<4;nt++)
        acc[rt][nt] = MFMA(a[rt], b[nt], acc[rt][nt], 0,0,0);
  }
  #pragma unroll
  for (int rt=0;rt<4;rt++){
    int rbase = m0 + rt*16 + (lane>>4)*4;
    #pragma unroll
    for (int nt=0;nt<4;nt++){
      int col = n0 + nt*16 + l15;
      #pragma unroll
      for (int j=0;j<4;j++)
        out[(size_t)(rbase+j)*nTot + col] = f2b(acc[rt][nt][j]);
    }
  }
}

// fp8 variant (for eih). grid (1024, nTot/256).
__global__ __launch_bounds__(256) void k_proj_f8(const u16* __restrict__ enc,
    const u16* __restrict__ W, u8* __restrict__ out, int nTot)
{
  int m0 = blockIdx.x*64;
  int tid = threadIdx.x, wv = tid>>6, lane = tid&63;
  int l15 = lane&15, kg = (lane>>4)*8;
  int n0 = blockIdx.y*256 + wv*64;
  f32x4 acc[4][4];
  #pragma unroll
  for (int rt=0;rt<4;rt++)
    #pragma unroll
    for (int nt=0;nt<4;nt++) acc[rt][nt] = (f32x4){0.f,0.f,0.f,0.f};
  for (int ko=0; ko<512; ko+=32){
    s16x8 a[4], b[4];
    #pragma unroll
    for (int rt=0;rt<4;rt++) a[rt] = *(const s16x8*)(enc + (size_t)(m0+rt*16+l15)*H2 + ko + kg);
    #pragma unroll
    for (int nt=0;nt<4;nt++) b[nt] = *(const s16x8*)(W + (size_t)(n0+nt*16+l15)*H2 + ko + kg);
    #pragma unroll
    for (int rt=0;rt<4;rt++)
      #pragma unroll
      for (int nt=0;nt<4;nt++)
        acc[rt][nt] = MFMA(a[rt], b[nt], acc[rt][nt], 0,0,0);
  }
  #pragma unroll
  for (int rt=0;rt<4;rt++){
    int rbase = m0 + rt*16 + (lane>>4)*4;
    #pragma unroll
    for (int nt=0;nt<4;nt++){
      int col = n0 + nt*16 + l15;
      #pragma unroll
      for (int j=0;j<4;j++)
        out[(size_t)(rbase+j)*nTot + col] = f2f8(acc[rt][nt][j]);
    }
  }
}

// e2 = enc @ W2^T (nTot=64). grid(1024), block 256 (4 waves: 1 col-tile each).
__global__ __launch_bounds__(256) void k_proj64(const u16* __restrict__ enc,
    const u16* __restrict__ W2, u16* __restrict__ out)
{
  int m0 = blockIdx.x*64;
  int tid = threadIdx.x, wv = tid>>6, lane = tid&63;
  int l15 = lane&15, kg = (lane>>4)*8;
  int n0 = wv*16;
  f32x4 acc[4];
  #pragma unroll
  for (int rt=0;rt<4;rt++) acc[rt] = (f32x4){0.f,0.f,0.f,0.f};
  for (int ko=0; ko<512; ko+=32){
    s16x8 b = *(const s16x8*)(W2 + (size_t)(n0+l15)*H2 + ko + kg);
    #pragma unroll
    for (int rt=0;rt<4;rt++){
      s16x8 a = *(const s16x8*)(enc + (size_t)(m0+rt*16+l15)*H2 + ko + kg);
      acc[rt] = MFMA(a, b, acc[rt], 0,0,0);
    }
  }
  #pragma unroll
  for (int rt=0;rt<4;rt++){
    int rbase = m0 + rt*16 + (lane>>4)*4;
    int col = n0 + l15;
    #pragma unroll
    for (int j=0;j<4;j++)
      out[(size_t)(rbase+j)*64 + col] = f2b(acc[rt][j]);
  }
}

// hidden = tanh([h_f|h_b] @ bridge_W^T + b) -> hst. grid (4,8).
__global__ __launch_bounds__(256) void k_bridge(const float* __restrict__ h_f,
    const float* __restrict__ h_b, const float* __restrict__ bw,
    const float* __restrict__ bb, float* __restrict__ hst)
{
  __shared__ float As[32][68];
  __shared__ float Ws[32][68];
  int n0=blockIdx.x*64, m0=blockIdx.y*64, tid=threadIdx.x;
  int ar=tid>>2, ak=(tid&3)*8;
  int rt=tid>>4, ct=tid&15;
  float acc[4][4];
  #pragma unroll
  for (int j=0;j<4;j++){
    #pragma unroll
    for (int l=0;l<4;l++) acc[j][l]=0.f;
  }
  for (int ko=0;ko<512;ko+=32){
    int k0=ko+ak;
    const float* asrc = (k0<256)? (h_f + (size_t)(m0+ar)*HH + k0)
                                : (h_b + (size_t)(m0+ar)*HH + (k0-256));
    float4 a0=*(const float4*)asrc, a1=*(const float4*)(asrc+4);
    const float* wsrc = bw + (size_t)(n0+ar)*H2 + k0;
    float4 w0=*(const float4*)wsrc, w1=*(const float4*)(wsrc+4);
    __syncthreads();
    As[ak+0][ar]=a0.x; As[ak+1][ar]=a0.y; As[ak+2][ar]=a0.z; As[ak+3][ar]=a0.w;
    As[ak+4][ar]=a1.x; As[ak+5][ar]=a1.y; As[ak+6][ar]=a1.z; As[ak+7][ar]=a1.w;
    Ws[ak+0][ar]=w0.x; Ws[ak+1][ar]=w0.y; Ws[ak+2][ar]=w0.z; Ws[ak+3][ar]=w0.w;
    Ws[ak+4][ar]=w1.x; Ws[ak+5][ar]=w1.y; Ws[ak+6][ar]=w1.z; Ws[ak+7][ar]=w1.w;
    __syncthreads();
    #pragma unroll
    for (int kk=0;kk<32;kk++){
      float4 a=*(const float4*)&As[kk][rt*4];
      float4 w=*(const float4*)&Ws[kk][ct*4];
      float a4[4]={a.x,a.y,a.z,a.w};
      float w4[4]={w.x,w.y,w.z,w.w};
      #pragma unroll
      for (int j=0;j<4;j++){
        #pragma unroll
        for (int l=0;l<4;l++) acc[j][l]+=a4[j]*w4[l];
      }
    }
  }
  #pragma unroll
  for (int j=0;j<4;j++){
    int row=m0+rt*4+j;
    #pragma unroll
    for (int l=0;l<4;l++){
      int col=n0+ct*4+l;
      hst[(size_t)row*HH+col]=tanh1(acc[j][l]+bb[col]);
    }
  }
}

// Bootstrap: q0 = h0@Wq, gh0 = h0@Whh, zero nll. grid(32), block 256.
__global__ __launch_bounds__(256) void k_boot(
    const float* __restrict__ hst, const u16* __restrict__ whh,
    const u16* __restrict__ wq, float* __restrict__ ghg,
    float* __restrict__ qg, float* __restrict__ nll)
{
  __shared__ u16 hsb[16][264];
  int bx=blockIdx.x, tid=threadIdx.x;
  int wv=tid>>6, lane=tid&63, l15=lane&15, kg=(lane>>4)*8;
  int b0=bx*16;
  {
    int c=tid;
    for (int r=0;r<16;r++) hsb[r][c] = f2b(hst[(size_t)(b0+r)*HH + c]);
  }
  if (tid<16) nll[b0+tid] = 0.f;
  __syncthreads();
  int rr = (lane>>4)*4;
  for (int nt=0;nt<12;nt++){
    int n0 = wv*192 + nt*16;
    f32x4 acc = (f32x4){0.f,0.f,0.f,0.f};
    for (int ko=0;ko<256;ko+=32){
      s16x8 a = *(const s16x8*)&hsb[l15][ko+kg];
      s16x8 bf = *(const s16x8*)(whh + (size_t)(n0+l15)*HH + ko + kg);
      acc = MFMA(a, bf, acc, 0,0,0);
    }
    #pragma unroll
    for (int jr=0;jr<4;jr++)
      ghg[(size_t)(b0+rr+jr)*H3 + n0 + l15] = acc[jr];
  }
  #pragma unroll
  for (int nt=0;nt<4;nt++){
    int n0 = wv*64 + nt*16;
    f32x4 acc = (f32x4){0.f,0.f,0.f,0.f};
    for (int ko=0;ko<256;ko+=32){
      s16x8 a = *(const s16x8*)&hsb[l15][ko+kg];
      s16x8 bf = *(const s16x8*)(wq + (size_t)(n0+l15)*HH + ko + kg);
      acc = MFMA(a, bf, acc, 0,0,0);
    }
    #pragma unroll
    for (int jr=0;jr<4;jr++)
      qg[(size_t)(b0+rr+jr)*HH + n0 + l15] = acc[jr];
  }
}

// ---------------------------------------------------------------------------
// Per-step kernel. grid(512) x 512 (2 blocks/CU).
// Blocks 0..31 (L>0): gates->h_L (gic from prev launch), q_L -> flag, gh_L,
// logits = tab_lgt + lgc + h@W3, nll. ALL blocks: attention row bx at step L:
// e/softmax, then gic_L = a @ eih8 (fp8), lgc_L = a @ e2.
__global__ __launch_bounds__(512,4) void k_step(int L,
    const int* __restrict__ input,
    const float* __restrict__ tab_dec, const float* __restrict__ tab_lgt,
    const float* __restrict__ bhh, const float* __restrict__ We,
    const u16* __restrict__ whh, const u16* __restrict__ wq,
    const u16* __restrict__ w3,
    const u16* __restrict__ pk, const u8* __restrict__ eih8,
    const u16* __restrict__ e2,
    float* __restrict__ hst, u32* __restrict__ qgu, float* __restrict__ ghg,
    u16* __restrict__ gicW, const u16* __restrict__ gicR,
    u16* __restrict__ lgcW, const u16* __restrict__ lgcR,
    float* __restrict__ nll, u32* __restrict__ fl)
{
  __shared__ __align__(16) char smem[40960];
  // gemm views
  u16 (*gicL)[776] = (u16(*)[776])smem;                 // 24832
  u16 (*lgcL)[64]  = (u16(*)[64])(smem+24832);          //  2048
  u16 (*hsb)[264]  = (u16(*)[264])(smem+26880);         //  8448
  float (*lgt)[64] = (float(*)[64])(smem+35328);        //  4096
  int* stokG       = (int*)(smem+39424);                //    64
  // attn views
  float* aL  = (float*)smem;                            // 512
  int* stok  = (int*)(smem+512);                        // 512
  float* qS  = (float*)(smem+1024);                     // 1024
  float (*pG)[768] = (float(*)[768])(smem+4096);        // 24576
  float (*pE)[64]  = (float(*)[64])(smem+28672);        //  2048

  int bx=blockIdx.x, tid=threadIdx.x;
  int wv=tid>>6, lane=tid&63, l15=lane&15, kg=(lane>>4)*8;

  // ======== GEMM part: blocks 0..31, step s=L-1 ========
  if (bx < 32 && L > 0){
    int s = L-1;
    int b0 = bx*16;
    int rr = (lane>>4)*4;
    float b_r, b_z, b_n;
    { int c=tid&255; b_r=bhh[c]; b_z=bhh[c+256]; b_n=bhh[c+512]; }
    for (int idx=tid; idx<6144; idx+=512){
      int r = idx/384, k = idx - r*384;
      *(u32*)&gicL[r][2*k] = *(const u32*)(gicR + (size_t)(b0+r)*H3 + 2*k);
    }
    { int r=tid>>5, k=tid&31;
      *(u32*)&lgcL[r][2*k] = *(const u32*)(lgcR + (size_t)(b0+r)*64 + 2*k); }
    if (tid<16) stokG[tid] = input[(b0+tid)*TT + s];
    __syncthreads();
    // gates -> h_L
    {
      int c = tid&255, rh = tid>>8;
      for (int r=rh*8; r<rh*8+8; r++){
        int bb = b0+r;
        const float* tg = tab_dec + (size_t)stokG[r]*H3;
        const float* gr = ghg + (size_t)bb*H3;
        float rg = sigm(tg[c]     + b2f(gicL[r][c])     + gr[c]     + b_r);
        float zg = sigm(tg[c+256] + b2f(gicL[r][c+256]) + gr[c+256] + b_z);
        float ng = tanh1(tg[c+512] + b2f(gicL[r][c+512]) + rg*(gr[c+512] + b_n));
        float hv = (1.f-zg)*ng + zg*hst[(size_t)bb*HH + c];
        hst[(size_t)bb*HH + c] = hv;
        hsb[r][c] = f2b(hv);
      }
    }
    __syncthreads();
    // q_L -> astore -> flag
    {
      f32x4 accq[2];
      accq[0]=(f32x4){0.f,0.f,0.f,0.f}; accq[1]=(f32x4){0.f,0.f,0.f,0.f};
      #pragma unroll
      for (int ko=0;ko<256;ko+=32){
        s16x8 bq0 = *(const s16x8*)(wq + (size_t)(wv*32+l15)*HH + ko + kg);
        s16x8 bq1 = *(const s16x8*)(wq + (size_t)(wv*32+16+l15)*HH + ko + kg);
        s16x8 a = *(const s16x8*)&hsb[l15][ko+kg];
        accq[0] = MFMA(a,bq0,accq[0],0,0,0);
        accq[1] = MFMA(a,bq1,accq[1],0,0,0);
      }
      #pragma unroll
      for (int nt=0;nt<2;nt++)
        #pragma unroll
        for (int jr=0;jr<4;jr++)
          astore(qgu + (size_t)(b0+rr+jr)*HH + wv*32+nt*16+l15,
                 __float_as_uint(accq[nt][jr]));
    }
    __syncthreads();
    if (tid==0) astore(&fl[QF(bx)], (u32)L);
    // gh_L
    {
      f32x4 acc6[6];
      #pragma unroll
      for (int nt=0;nt<6;nt++) acc6[nt]=(f32x4){0.f,0.f,0.f,0.f};
      #pragma unroll
      for (int ko=0;ko<256;ko+=32){
        s16x8 b6[6];
        #pragma unroll
        for (int nt=0;nt<6;nt++)
          b6[nt] = *(const s16x8*)(whh + (size_t)(wv*96+nt*16+l15)*HH + ko + kg);
        s16x8 a = *(const s16x8*)&hsb[l15][ko+kg];
        #pragma unroll
        for (int nt=0;nt<6;nt++) acc6[nt]=MFMA(a,b6[nt],acc6[nt],0,0,0);
      }
      #pragma unroll
      for (int nt=0;nt<6;nt++)
        #pragma unroll
        for (int jr=0;jr<4;jr++)
          ghg[(size_t)(b0+rr+jr)*H3 + wv*96+nt*16+l15] = acc6[nt][jr];
    }
    // logits = tab_lgt[tok] + lgc + h @ W3^T (N=64): waves 0..3
    if (wv<4){
      int n0 = wv*16;
      f32x4 acc = (f32x4){0.f,0.f,0.f,0.f};
      for (int ko=0;ko<256;ko+=32){
        s16x8 a = *(const s16x8*)&hsb[l15][ko+kg];
        s16x8 bf = *(const s16x8*)(w3 + (size_t)(n0+l15)*HH + ko + kg);
        acc = MFMA(a,bf,acc,0,0,0);
      }
      #pragma unroll
      for (int jr=0;jr<4;jr++){
        int r = rr+jr, col = n0+l15;
        lgt[r][col] = acc[jr] + tab_lgt[(size_t)stokG[r]*64 + col]
                    + b2f(lgcL[r][col]);
      }
    }
    __syncthreads();
    // nll
    {
      int r = wv*4 + (lane>>4);
      if (r < 16){
        float v0 = lgt[r][l15];
        float v1 = lgt[r][l15+16];
        float v2 = (l15<7)? lgt[r][l15+32] : NEGF;
        float m = fmaxf(fmaxf(v0,v1),v2);
        #pragma unroll
        for (int off=8; off; off>>=1) m = fmaxf(m, __shfl_xor(m,off));
        float pe = __expf(v0-m) + __expf(v1-m) + ((l15<7)? __expf(v2-m) : 0.f);
        #pragma unroll
        for (int off=8; off; off>>=1) pe += __shfl_xor(pe,off);
        if (l15==0){
          int ty = input[(b0+r)*TT + s+1];
          if (ty != 0) nll[b0+r] += m + __logf(pe) - lgt[r][ty];
        }
      }
    }
    __syncthreads();
  }

  // ======== Attention part: all blocks, row bx, step L ========
  if (L < TM1){
    int r2 = bx;
    int g2 = r2>>4;
    int l32 = lane&31;
    if (tid < TT) stok[tid] = input[r2*TT + tid];
    const u16* pkb = pk + (size_t)r2*TT*HH + l32*8;
    s16x8 kv[8];
    #pragma unroll
    for (int it=0; it<8; it++){
      int t = wv*16 + it*2 + (lane>>5);
      kv[it] = *(const s16x8*)(pkb + (size_t)t*HH);
    }
    float4 w0 = *(const float4*)(We + l32*8);
    float4 w1 = *(const float4*)(We + l32*8 + 4);
    __syncthreads();
    if (L > 0){
      if (tid==0){
        while (aload(&fl[QF(g2)]) < (u32)L) __builtin_amdgcn_s_sleep(1);
      }
      __syncthreads();
    }
    if (tid < 256) qS[tid] = __uint_as_float(aload(qgu + (size_t)r2*HH + tid));
    __syncthreads();
    float4 q0 = *(const float4*)&qS[l32*8];
    float4 q1 = *(const float4*)&qS[l32*8 + 4];
    #pragma unroll
    for (int it=0; it<8; it++){
      int t = wv*16 + it*2 + (lane>>5);
      s16x8 k8 = kv[it];
      float sE = tanh1(q0.x + b2f((u16)k8[0]))*w0.x
               + tanh1(q0.y + b2f((u16)k8[1]))*w0.y
               + tanh1(q0.z + b2f((u16)k8[2]))*w0.z
               + tanh1(q0.w + b2f((u16)k8[3]))*w0.w
               + tanh1(q1.x + b2f((u16)k8[4]))*w1.x
               + tanh1(q1.y + b2f((u16)k8[5]))*w1.y
               + tanh1(q1.z + b2f((u16)k8[6]))*w1.z
               + tanh1(q1.w + b2f((u16)k8[7]))*w1.w;
      #pragma unroll
      for (int off=16; off; off>>=1) sE += __shfl_xor(sE, off);
      if (l32==0) aL[t] = stok[t] ? sE : NEGF;
    }
    __syncthreads();
    if (wv==0){
      float v0 = aL[lane], v1 = aL[64+lane];
      float m = fmaxf(v0,v1);
      #pragma unroll
      for (int off=32; off; off>>=1) m = fmaxf(m, __shfl_xor(m,off));
      float p0 = __expf(v0-m), p1 = __expf(v1-m);
      float sS = p0+p1;
      #pragma unroll
      for (int off=32; off; off>>=1) sS += __shfl_xor(sS,off);
      float inv = 1.f/sS;
      aL[lane] = p0*inv; aL[64+lane] = p1*inv;
    }
    __syncthreads();
    // gic_L = a @ eih8 (fp8); lgc_L = a @ e2 (wave: 16 t's)
    {
      float gA[8], gB[4], eA=0.f;
      #pragma unroll
      for (int e=0;e<8;e++) gA[e]=0.f;
      #pragma unroll
      for (int e=0;e<4;e++) gB[e]=0.f;
      const u8* ei = eih8 + (size_t)r2*TT*H3;
      const u16* ee = e2 + (size_t)r2*TT*64;
      int t0 = wv*16;
      #pragma unroll 4
      for (int tt=0; tt<16; tt++){
        int t = t0+tt;
        float a = aL[t];
        u32x2 v0 = *(const u32x2*)(ei + (size_t)t*H3 + lane*8);
        u32 v1 = *(const u32*)(ei + (size_t)t*H3 + 512 + lane*4);
        float ev = b2f(ee[(size_t)t*64 + lane]);
        gA[0]+=a*f8f(v0.x); gA[1]+=a*f8f(v0.x>>8);
        gA[2]+=a*f8f(v0.x>>16); gA[3]+=a*f8f(v0.x>>24);
        gA[4]+=a*f8f(v0.y); gA[5]+=a*f8f(v0.y>>8);
        gA[6]+=a*f8f(v0.y>>16); gA[7]+=a*f8f(v0.y>>24);
        gB[0]+=a*f8f(v1); gB[1]+=a*f8f(v1>>8);
        gB[2]+=a*f8f(v1>>16); gB[3]+=a*f8f(v1>>24);
        eA += a*ev;
      }
      #pragma unroll
      for (int e=0;e<8;e++) pG[wv][lane*8+e] = gA[e];
      #pragma unroll
      for (int e=0;e<4;e++) pG[wv][512+lane*4+e] = gB[e];
      pE[wv][lane] = eA;
    }
    __syncthreads();
    // reduce + plain stores: gic (768 u16) + lgc (64 u16); read next launch
    if (tid < 384){
      float lo=0.f, hi=0.f;
      #pragma unroll
      for (int w=0;w<8;w++){ lo += pG[w][2*tid]; hi += pG[w][2*tid+1]; }
      u32 v = (u32)f2b(lo) | ((u32)f2b(hi)<<16);
      *(u32*)&gicW[(size_t)r2*H3 + 2*tid] = v;
    } else if (tid < 416){
      int d = tid-384;
      float lo=0.f, hi=0.f;
      #pragma unroll
      for (int w=0;w<8;w++){ lo += pE[w][2*d]; hi += pE[w][2*d+1]; }
      u32 v = (u32)f2b(lo) | ((u32)f2b(hi)<<16);
      *(u32*)&lgcW[(size_t)r2*64 + 2*d] = v;
    }
  }
}

__global__ __launch_bounds__(256) void k_loss(const float* __restrict__ nll,
                                              float* __restrict__ out)
{
  __shared__ float sm[256];
  int tid=threadIdx.x;
  float s = nll[tid] + nll[tid+256];
  sm[tid]=s; __syncthreads();
  for (int off=128; off; off>>=1){
    if (tid<off) sm[tid]+=sm[tid+off];
    __syncthreads();
  }
  if (tid==0) out[0]=sm[0];
}

extern "C" void kernel_launch(void* const* d_in, const int* in_sizes, int n_in,
                              void* d_out, int out_size, void* d_ws, size_t ws_size,
                              hipStream_t stream)
{
  const int*   input    = (const int*)  d_in[0];
  const float* src_emb  = (const float*)d_in[1];
  const float* trg_emb  = (const float*)d_in[2];
  const float* eWih_f   = (const float*)d_in[3];
  const float* eWhh_f   = (const float*)d_in[4];
  const float* ebih_f   = (const float*)d_in[5];
  const float* ebhh_f   = (const float*)d_in[6];
  const float* eWih_b   = (const float*)d_in[7];
  const float* eWhh_b   = (const float*)d_in[8];
  const float* ebih_b   = (const float*)d_in[9];
  const float* ebhh_b   = (const float*)d_in[10];
  const float* bridge_W = (const float*)d_in[11];
  const float* bridge_b = (const float*)d_in[12];
  const float* attn_Wk  = (const float*)d_in[13];
  const float* attn_Wq  = (const float*)d_in[14];
  const float* attn_We  = (const float*)d_in[15];
  const float* dec_Wih  = (const float*)d_in[16];
  const float* dec_Whh  = (const float*)d_in[17];
  const float* dec_bih  = (const float*)d_in[18];
  const float* dec_bhh  = (const float*)d_in[19];
  const float* pre_W    = (const float*)d_in[20];
  const float* gen_W    = (const float*)d_in[21];

  float* F = (float*)d_ws;
  size_t o=0;
  u32* fl         = (u32*)(F+o); o+=2048;
  float* tab_gi_f = F+o; o+=(size_t)VV*H3;
  float* tab_gi_b = F+o; o+=(size_t)VV*H3;
  float* tab_dec  = F+o; o+=(size_t)VV*H3;
  float* tab_pre  = F+o; o+=(size_t)VV*HH;
  float* tab_lgt  = F+o; o+=(size_t)VV*64;
  float* h_f      = F+o; o+=(size_t)BB*HH;
  float* h_b      = F+o; o+=(size_t)BB*HH;
  float* hst      = F+o; o+=(size_t)BB*HH;
  float* qg       = F+o; o+=(size_t)BB*HH;
  float* ghg      = F+o; o+=(size_t)BB*H3;
  float* nll      = F+o; o+=(size_t)BB;
  u16* U = (u16*)(F+o);
  size_t uo=0;
  u16* enc_out = U+uo; uo+=(size_t)BB*TT*H2;
  u16* pk      = U+uo; uo+=(size_t)BB*TT*HH;
  u16* e2      = U+uo; uo+=(size_t)BB*TT*64;
  u16* gic0    = U+uo; uo+=(size_t)BB*H3;
  u16* gic1    = U+uo; uo+=(size_t)BB*H3;
  u16* lgc0    = U+uo; uo+=(size_t)BB*64;
  u16* lgc1    = U+uo; uo+=(size_t)BB*64;
  u16* wb_ehh_f= U+uo; uo+=(size_t)H3*HH;
  u16* wb_ehh_b= U+uo; uo+=(size_t)H3*HH;
  u16* wb_dhh  = U+uo; uo+=(size_t)H3*HH;
  u16* wb_dih  = U+uo; uo+=(size_t)H3*H2;
  u16* wb_wk   = U+uo; uo+=(size_t)HH*H2;
  u16* wb_wq   = U+uo; uo+=(size_t)HH*HH;
  u16* wb_w2   = U+uo; uo+=(size_t)64*H2;
  u16* wb_w3   = U+uo; uo+=(size_t)64*HH;
  u8* eih8 = (u8*)(U+uo);   // [BB][TT][768] fp8

  dim3 blk(256,1,1);
  k_tables<<<dim3(VV,10),blk,0,stream>>>(src_emb,trg_emb,eWih_f,ebih_f,eWih_b,ebih_b,
                                         dec_Wih,dec_bih,pre_W,
                                         tab_gi_f,tab_gi_b,tab_dec,tab_pre);
  k_tlg<<<dim3(VV),blk,0,stream>>>(tab_pre,gen_W,tab_lgt);
  k_cvt_all<<<dim3(4608),blk,0,stream>>>(eWhh_f,eWhh_b,dec_Whh,dec_Wih,attn_Wk,attn_Wq,
                                         wb_ehh_f,wb_ehh_b,wb_dhh,wb_dih,wb_wk,wb_wq);
  k_w2<<<dim3(128),blk,0,stream>>>(gen_W,pre_W,wb_w2);
  k_w3<<<dim3(64),blk,0,stream>>>(gen_W,pre_W,wb_w3);
  k_enc_all<<<dim3(512),dim3(512),0,stream>>>(input,wb_ehh_f,wb_ehh_b,ebhh_f,ebhh_b,
                                              tab_gi_f,tab_gi_b,h_f,h_b,enc_out);
  k_proj<<<dim3(1024,1),blk,0,stream>>>(enc_out,wb_wk,pk,HH);
  k_proj_f8<<<dim3(1024,3),blk,0,stream>>>(enc_out,wb_dih,eih8,H3);
  k_proj64<<<dim3(1024),blk,0,stream>>>(enc_out,wb_w2,e2);
  k_bridge<<<dim3(4,8),blk,0,stream>>>(h_f,h_b,bridge_W,bridge_b,hst);
  k_boot<<<dim3(32),blk,0,stream>>>(hst,wb_dhh,wb_wq,ghg,qg,nll);
  hipMemsetAsync(fl, 0, 8192, stream);

  for (int L=0; L<=TM1; L++){
    u16* gw = (L&1)? gic1 : gic0;
    u16* gr = (L&1)? gic0 : gic1;
    u16* lw = (L&1)? lgc1 : lgc0;
    u16* lr = (L&1)? lgc0 : lgc1;
    k_step<<<dim3(512),dim3(512),0,stream>>>(L,input,tab_dec,tab_lgt,dec_bhh,attn_We,
                                             wb_dhh,wb_wq,wb_w3,
                                             pk,eih8,e2,hst,(u32*)qg,ghg,
                                             gw,gr,lw,lr,nll,fl);
  }
  k_loss<<<dim3(1),blk,0,stream>>>(nll,(float*)d_out);
}